// Round 7
// baseline (208.715 us; speedup 1.0000x reference)
//
#include <hip/hip_runtime.h>
#include <math.h>

// BCE + distance-correlation loss, N=8192 fp32 — single fused kernel.
//
// Expansion (raw weights w, W=sum w, s=N/W):
//   S_XY = s^2*T1xy - (2 s^3/N)*sum_i w_i RX_i RY_i + (s^4/N^2)*CX*CY
//   T1ab = sum_ij w_i w_j |x_i-x_j||e_i-e_j|        (needs N^2)
//   T1aa = 2(W*Sxx - Sx^2)   (closed form),  T1bb = 2(W*See - Se^2)
//   RX_i = sum_j w_j |x_i-x_j|,  CX = sum_i w_i RX_i
//
// One dispatch, three phases chained by device-scope atomic counters
// (Guideline 16: device-scope atomics+fences are the sanctioned cross-XCD
// handshake):
//  phase 1 (all 1024 blocks): tile pass -> T1ab partials + float2 row partials
//  phase 2 (last 32 arrivals; <=31 blocks still in flight, so the spin is
//           short and deadlock-free): column-sum partials + 12 scalars
//  phase 3 (last phase-2 block): combine + write out.
// Chunk assignment is by arrival rank -> work per chunk is fixed -> bit-exact.
//
// ws: uint ctr[2] @0 (zeroed by a 64B memset); double tpart[1024] @64;
//     float2 PP[128][N] @16K; double spart[32][12] after PP.

#define BLK  256
#define RPT  4                 // rows/thread -> i-tile 1024
#define JLEN 64                // j-chunk per block
#define NJS  128               // n/JLEN
#define NIT  8                 // n/(BLK*RPT)
#define NBLK (NIT * NJS)       // 1024
#define P2B  32                // phase-2 blocks
#define NSC  12

__device__ inline double waveReduceD(double v) {
    for (int off = 32; off > 0; off >>= 1) v += __shfl_down(v, off, 64);
    return v;
}

// valid in threadIdx.x==0
__device__ inline double blockReduceD(double v, double* lds) {
    int lane = threadIdx.x & 63, wid = threadIdx.x >> 6;
    v = waveReduceD(v);
    if (lane == 0) lds[wid] = v;
    __syncthreads();
    double r = 0.0;
    if (wid == 0) {
        int nw = blockDim.x >> 6;
        r = (lane < nw) ? lds[lane] : 0.0;
        r = waveReduceD(r);
    }
    __syncthreads();
    return r;
}

__global__ __launch_bounds__(BLK) void mega(
        const float* __restrict__ x, const float* __restrict__ lab,
        const float* __restrict__ e, const float* __restrict__ w,
        int n, unsigned int* __restrict__ ctr, double* __restrict__ tpart,
        float2* __restrict__ PP, double* __restrict__ spart,
        float* __restrict__ out) {
    __shared__ float4 sj[JLEN];
    __shared__ double lds[BLK / 64];
    __shared__ double sk[NSC];
    __shared__ unsigned int rank_s;

    int t = threadIdx.x;
    int bid = blockIdx.x;
    int it = bid & (NIT - 1);        // i-tile   (bid % 8)
    int tj = bid >> 3;               // j-split  (bid / 8)

    // ---------- phase 1: tile pass ----------
    int j0 = tj * JLEN;
    if (t < JLEN) {
        int j = j0 + t;
        sj[t] = make_float4(x[j], e[j], w[j], 0.f);
    }
    __syncthreads();

    int i0 = it * (BLK * RPT) + t;
    float xi[RPT], ei[RPT], ra[RPT], rb[RPT], ab[RPT];
#pragma unroll
    for (int r = 0; r < RPT; ++r) {
        int i = i0 + r * BLK;
        xi[r] = x[i]; ei[r] = e[i];
        ra[r] = 0.f; rb[r] = 0.f; ab[r] = 0.f;
    }
#pragma unroll 4
    for (int k = 0; k < JLEN; ++k) {
        float4 j4 = sj[k];                           // LDS broadcast, conflict-free
        float xj = j4.x, ej = j4.y, wj = j4.z;
#pragma unroll
        for (int r = 0; r < RPT; ++r) {
            float a = fabsf(xi[r] - xj);
            float b = fabsf(ei[r] - ej);
            ra[r] = fmaf(wj, a, ra[r]);
            rb[r] = fmaf(wj, b, rb[r]);
            ab[r] = fmaf(wj, a * b, ab[r]);          // w_i applied below
        }
    }
    double tab = 0.0;
#pragma unroll
    for (int r = 0; r < RPT; ++r) {
        int i = i0 + r * BLK;
        tab += (double)(w[i] * ab[r]);
        PP[(size_t)tj * n + i] = make_float2(ra[r], rb[r]);  // coalesced 8B stores
    }
    tab = blockReduceD(tab, lds);
    if (t == 0) tpart[bid] = tab;

    // ---------- arrival / rank ----------
    __threadfence();                                  // release PP/tpart (device scope)
    if (t == 0) rank_s = atomicAdd(&ctr[0], 1u);
    __syncthreads();
    unsigned int rank = rank_s;
    if (rank < NBLK - P2B) return;                    // early arrivals exit

    if (t == 0) {                                     // wait for all phase-1 writers
        while (atomicAdd(&ctr[0], 0u) < NBLK) __builtin_amdgcn_s_sleep(2);
    }
    __syncthreads();
    __threadfence();                                  // acquire

    // ---------- phase 2: column sums + scalars (32 blocks) ----------
    int chunk = (int)rank - (NBLK - P2B);             // 0..31
    int i = chunk * 256 + t;
    double rai = 0.0, rbi = 0.0;
    for (int p0 = 0; p0 < NJS; p0 += 16) {            // 16 outstanding 8B loads
        float2 v[16];
#pragma unroll
        for (int q = 0; q < 16; ++q) v[q] = PP[(size_t)(p0 + q) * n + i];
#pragma unroll
        for (int q = 0; q < 16; ++q) { rai += (double)v[q].x; rbi += (double)v[q].y; }
    }
    double wi = (double)w[i];
    double xi2 = (double)x[i], ei2 = (double)e[i], yi = (double)lab[i];
    float xf = x[i];
    float sp = fmaxf(xf, 0.f) + log1pf(expf(-fabsf(xf)));   // stable softplus
    double acc[NSC];
    acc[0]  = wi;                            // W
    acc[1]  = ((double)sp - xi2 * yi) * wi;  // BCE sum
    acc[2]  = wi * rai * rbi;                // AB
    acc[3]  = wi * rai * rai;                // AA
    acc[4]  = wi * rbi * rbi;                // BB
    acc[5]  = wi * rai;                      // CA
    acc[6]  = wi * rbi;                      // CB
    acc[7]  = wi * xi2;                      // Sx
    acc[8]  = wi * xi2 * xi2;                // Sxx
    acc[9]  = wi * ei2;                      // Se
    acc[10] = wi * ei2 * ei2;                // See
    acc[11] = (i < NBLK) ? tpart[i] : 0.0;   // T1ab partial fold-in
#pragma unroll
    for (int k = 0; k < NSC; ++k) {
        double r = blockReduceD(acc[k], lds);
        if (t == 0) spart[chunk * NSC + k] = r;
    }

    // ---------- phase 3: last phase-2 block combines ----------
    __threadfence();
    if (t == 0) rank_s = atomicAdd(&ctr[1], 1u);
    __syncthreads();
    if (rank_s == P2B - 1) {
        __threadfence();
        if (t < NSC) {
            double s = 0.0;
            for (int p = 0; p < P2B; ++p) s += spart[p * NSC + t];
            sk[t] = s;
        }
        __syncthreads();
        if (t == 0) {
            double W = sk[0], BCE = sk[1], AB = sk[2], AA = sk[3], BB = sk[4];
            double CA = sk[5], CB = sk[6], Sx = sk[7], Sxx = sk[8];
            double Se = sk[9], See = sk[10], T1ab = sk[11];
            double N = (double)n;
            double T1aa = 2.0 * (W * Sxx - Sx * Sx);
            double T1bb = 2.0 * (W * See - Se * Se);
            double s = N / W, s2 = s * s, s3 = s2 * s, s4 = s2 * s2;
            double Sab = s2 * T1ab - (2.0 * s3 / N) * AB + (s4 / (N * N)) * CA * CB;
            double Saa = s2 * T1aa - (2.0 * s3 / N) * AA + (s4 / (N * N)) * CA * CA;
            double Sbb = s2 * T1bb - (2.0 * s3 / N) * BB + (s4 / (N * N)) * CB * CB;
            double disco = Sab / sqrt(Saa * Sbb);
            double bce = BCE / N;
            out[0] = (float)bce;
            out[1] = (float)disco;
            out[2] = (float)(bce + 0.1 * disco);
        }
    }
}

extern "C" void kernel_launch(void* const* d_in, const int* in_sizes, int n_in,
                              void* d_out, int out_size, void* d_ws, size_t ws_size,
                              hipStream_t stream) {
    const float* outputs = (const float*)d_in[0];
    const float* labels  = (const float*)d_in[1];
    const float* event   = (const float*)d_in[2];
    const float* weights = (const float*)d_in[3];
    int n = in_sizes[0];

    unsigned int* ctr = (unsigned int*)d_ws;
    double* tpart = (double*)((char*)d_ws + 64);
    float2* PP = (float2*)((char*)d_ws + 16384);
    double* spart = (double*)((char*)d_ws + 16384 + (size_t)NJS * n * sizeof(float2));
    float* out = (float*)d_out;

    hipMemsetAsync(d_ws, 0, 64, stream);   // zero the two phase counters
    mega<<<NBLK, BLK, 0, stream>>>(outputs, labels, event, weights,
                                   n, ctr, tpart, PP, spart, out);
}

// Round 8
// 95.428 us; speedup vs baseline: 2.1871x; 2.1871x over previous
//
#include <hip/hip_runtime.h>
#include <math.h>

// BCE + distance-correlation loss, N=8192 fp32.
//
// Expansion (raw weights w, W=sum w, s=N/W):
//   S_XY = s^2*T1xy - (2 s^3/N)*sum_i w_i RX_i RY_i + (s^4/N^2)*CX*CY
//   T1ab = sum_ij w_i w_j |x_i-x_j||e_i-e_j|        (needs N^2)
//   T1aa = 2(W*Sxx - Sx^2)   (closed form),  T1bb = 2(W*See - Se^2)
//   RX_i = sum_j w_j |x_i-x_j|,  CX = sum_i w_i RX_i
//
// kf: N^2 pass (512 blocks, RPT=8 -> 24 indep FMA chains/thread, 1 LDS b128
//     broadcast per 48 VALU) -> T1ab partials + float2 row partials.
// kg: 32 blocks -> column sums + 12 scalars; last arrival (32-block counter
//     handshake — cheap, unlike round 7's 1024-block one) finalizes + writes.
// No atomwhy-floats, no large memsets, deterministic sums -> bit-stable.
//
// ws: uint ctr @0 (64B memset); double tpart[512] @64; float2 PP[128][N] @16K;
//     double spart[32][12] after PP.

#define BLK  256
#define RPT  8                 // rows/thread -> i-tile 2048
#define JLEN 64                // j-chunk per block
#define NJS  128               // n/JLEN
#define NSC  12
#define P2B  32                // kg blocks

__device__ inline double waveReduceD(double v) {
    for (int off = 32; off > 0; off >>= 1) v += __shfl_down(v, off, 64);
    return v;
}

// valid in threadIdx.x==0
__device__ inline double blockReduceD(double v, double* lds) {
    int lane = threadIdx.x & 63, wid = threadIdx.x >> 6;
    v = waveReduceD(v);
    if (lane == 0) lds[wid] = v;
    __syncthreads();
    double r = 0.0;
    if (wid == 0) {
        int nw = blockDim.x >> 6;
        r = (lane < nw) ? lds[lane] : 0.0;
        r = waveReduceD(r);
    }
    __syncthreads();
    return r;
}

// N^2 pass. grid = (n/(BLK*RPT), NJS) = (4, 128).
__global__ __launch_bounds__(BLK) void kf(
        const float* __restrict__ x, const float* __restrict__ e,
        const float* __restrict__ w, int n, double* __restrict__ tpart,
        float2* __restrict__ PP) {
    __shared__ float4 sj[JLEN];          // {x, e, w, 0} -> one b128 broadcast per k
    __shared__ double lds[BLK / 64];
    int t = threadIdx.x;
    int tj = blockIdx.y;
    int j0 = tj * JLEN;
    if (t < JLEN) {
        int j = j0 + t;
        sj[t] = make_float4(x[j], e[j], w[j], 0.f);
    }
    __syncthreads();

    int i0 = blockIdx.x * (BLK * RPT) + t;
    float xi[RPT], ei[RPT], ra[RPT], rb[RPT], ab[RPT];
#pragma unroll
    for (int r = 0; r < RPT; ++r) {
        int i = i0 + r * BLK;
        xi[r] = x[i]; ei[r] = e[i];
        ra[r] = 0.f; rb[r] = 0.f; ab[r] = 0.f;
    }

#pragma unroll 2
    for (int k = 0; k < JLEN; ++k) {
        float4 j4 = sj[k];                           // LDS broadcast, conflict-free
        float xj = j4.x, ej = j4.y, wj = j4.z;
#pragma unroll
        for (int r = 0; r < RPT; ++r) {              // 24 independent acc chains
            float a = fabsf(xi[r] - xj);
            float b = fabsf(ei[r] - ej);
            ra[r] = fmaf(wj, a, ra[r]);
            rb[r] = fmaf(wj, b, rb[r]);
            ab[r] = fmaf(wj, a * b, ab[r]);          // w_i applied below
        }
    }

    double tab = 0.0;
#pragma unroll
    for (int r = 0; r < RPT; ++r) {
        int i = i0 + r * BLK;
        tab += (double)(w[i] * ab[r]);
        PP[(size_t)tj * n + i] = make_float2(ra[r], rb[r]);  // coalesced 8B stores
    }
    tab = blockReduceD(tab, lds);
    if (t == 0) tpart[tj * gridDim.x + blockIdx.x] = tab;
}

// Column sums + scalars + finalize. grid = P2B blocks of 256.
__global__ __launch_bounds__(256) void kg(
        const float* __restrict__ x, const float* __restrict__ lab,
        const float* __restrict__ e, const float* __restrict__ w,
        const float2* __restrict__ PP, int n,
        const double* __restrict__ tpart, int ntp,
        double* __restrict__ spart, unsigned int* __restrict__ ctr,
        float* __restrict__ out) {
    __shared__ double lds[4];
    __shared__ double sk[NSC];
    __shared__ unsigned int rank_s;
    int t = threadIdx.x;
    int i = blockIdx.x * 256 + t;                    // deterministic chunk

    double rai = 0.0, rbi = 0.0;
    for (int p0 = 0; p0 < NJS; p0 += 16) {           // 16 outstanding 8B loads
        float2 v[16];
#pragma unroll
        for (int q = 0; q < 16; ++q) v[q] = PP[(size_t)(p0 + q) * n + i];
#pragma unroll
        for (int q = 0; q < 16; ++q) { rai += (double)v[q].x; rbi += (double)v[q].y; }
    }

    double wi = (double)w[i];
    double xi = (double)x[i], ei = (double)e[i], yi = (double)lab[i];
    float xf = x[i];
    float sp = fmaxf(xf, 0.f) + log1pf(expf(-fabsf(xf)));   // stable softplus
    double acc[NSC];
    acc[0]  = wi;                          // W
    acc[1]  = ((double)sp - xi * yi) * wi; // BCE sum
    acc[2]  = wi * rai * rbi;              // AB
    acc[3]  = wi * rai * rai;              // AA
    acc[4]  = wi * rbi * rbi;              // BB
    acc[5]  = wi * rai;                    // CA
    acc[6]  = wi * rbi;                    // CB
    acc[7]  = wi * xi;                     // Sx
    acc[8]  = wi * xi * xi;                // Sxx
    acc[9]  = wi * ei;                     // Se
    acc[10] = wi * ei * ei;                // See
    acc[11] = (i < ntp) ? tpart[i] : 0.0;  // T1ab partial fold-in
#pragma unroll
    for (int k = 0; k < NSC; ++k) {
        double r = blockReduceD(acc[k], lds);
        if (t == 0) spart[blockIdx.x * NSC + k] = r;
    }

    // 32-block handshake: last arrival finalizes (cheap at this scale).
    __threadfence();                                  // release spart
    if (t == 0) rank_s = atomicAdd(ctr, 1u);
    __syncthreads();
    if (rank_s == P2B - 1) {
        __threadfence();                              // acquire
        if (t < NSC) {
            double s = 0.0;
            for (int p = 0; p < P2B; ++p) s += spart[p * NSC + t];  // fixed order
            sk[t] = s;
        }
        __syncthreads();
        if (t == 0) {
            double W = sk[0], BCE = sk[1], AB = sk[2], AA = sk[3], BB = sk[4];
            double CA = sk[5], CB = sk[6], Sx = sk[7], Sxx = sk[8];
            double Se = sk[9], See = sk[10], T1ab = sk[11];
            double N = (double)n;
            double T1aa = 2.0 * (W * Sxx - Sx * Sx);
            double T1bb = 2.0 * (W * See - Se * Se);
            double s = N / W, s2 = s * s, s3 = s2 * s, s4 = s2 * s2;
            double Sab = s2 * T1ab - (2.0 * s3 / N) * AB + (s4 / (N * N)) * CA * CB;
            double Saa = s2 * T1aa - (2.0 * s3 / N) * AA + (s4 / (N * N)) * CA * CA;
            double Sbb = s2 * T1bb - (2.0 * s3 / N) * BB + (s4 / (N * N)) * CB * CB;
            double disco = Sab / sqrt(Saa * Sbb);
            double bce = BCE / N;
            out[0] = (float)bce;
            out[1] = (float)disco;
            out[2] = (float)(bce + 0.1 * disco);
        }
    }
}

extern "C" void kernel_launch(void* const* d_in, const int* in_sizes, int n_in,
                              void* d_out, int out_size, void* d_ws, size_t ws_size,
                              hipStream_t stream) {
    const float* outputs = (const float*)d_in[0];
    const float* labels  = (const float*)d_in[1];
    const float* event   = (const float*)d_in[2];
    const float* weights = (const float*)d_in[3];
    int n = in_sizes[0];

    int nit = n / (BLK * RPT);      // 4 i-tiles
    int ntp = NJS * nit;            // 512 T1ab partials

    unsigned int* ctr = (unsigned int*)d_ws;
    double* tpart = (double*)((char*)d_ws + 64);
    float2* PP = (float2*)((char*)d_ws + 16384);
    double* spart = (double*)((char*)d_ws + 16384 + (size_t)NJS * n * sizeof(float2));
    float* out = (float*)d_out;

    hipMemsetAsync(d_ws, 0, 64, stream);   // zero the handshake counter

    dim3 gF(nit, NJS);              // (4, 128) = 512 blocks
    kf<<<gF, BLK, 0, stream>>>(outputs, event, weights, n, tpart, PP);
    kg<<<P2B, 256, 0, stream>>>(outputs, labels, event, weights, PP,
                                n, tpart, ntp, spart, ctr, out);
}